// Round 4
// baseline (260.426 us; speedup 1.0000x reference)
//
#include <hip/hip_runtime.h>
#include <stdint.h>

// ---------------- constants ----------------
#define T_SEQ 2048
#define DM    2048
#define NH    16
#define HD    128
#define SB    204          // int(0.1*2048)
#define EV    1229         // 2048 - 819
#define RB    819          // int(0.4*2048)
#define NRECF 818.0f       // 2048 - (EV+1)
#define LAST_START 1792    // (2047//256)*256
#define SCALE 0.08838834764831845f  // 1/sqrt(128)

typedef __attribute__((ext_vector_type(8))) short short8;
typedef __attribute__((ext_vector_type(4))) short short4v;
typedef __attribute__((ext_vector_type(4))) float f32x4;

__device__ __forceinline__ unsigned short f2bf(float f) {
  uint32_t u = __float_as_uint(f);
  u += 0x7fffu + ((u >> 16) & 1u);   // RNE
  return (unsigned short)(u >> 16);
}
__device__ __forceinline__ float bf2f(unsigned short s) {
  return __uint_as_float(((uint32_t)s) << 16);
}
__device__ __forceinline__ void gload16(const void* g, void* l) {
  __builtin_amdgcn_global_load_lds((const __attribute__((address_space(1))) void*)g,
                                   (__attribute__((address_space(3))) void*)l,
                                   16, 0, 0);
}
__device__ __forceinline__ float n2n(float v) {
  if (isnan(v)) return 0.0f;
  if (isinf(v)) return v > 0.0f ? 10000.0f : -10000.0f;
  return v;
}

// ---------------- 1. fp32 -> bf16 conversions ----------------
__global__ __launch_bounds__(256) void cvt_kernel(
    const float* __restrict__ hs, const float* __restrict__ wq,
    const float* __restrict__ wk, const float* __restrict__ wv,
    const float* __restrict__ wo, unsigned short* __restrict__ hsb,
    unsigned short* __restrict__ wqb, unsigned short* __restrict__ wkb,
    unsigned short* __restrict__ wvb, unsigned short* __restrict__ wob) {
  int gid = blockIdx.x * 256 + threadIdx.x;
  int region = gid >> 20;
  int off4 = (gid & 1048575) * 4;
  const float* src; unsigned short* dst;
  switch (region) {
    case 0: src = hs; dst = hsb; break;
    case 1: src = wq; dst = wqb; break;
    case 2: src = wk; dst = wkb; break;
    case 3: src = wv; dst = wvb; break;
    default: src = wo; dst = wob; break;
  }
  float4 v = *(const float4*)(src + off4);
  if (region == 0) { v.x = n2n(v.x); v.y = n2n(v.y); v.z = n2n(v.z); v.w = n2n(v.w); }
  ushort4 o;
  o.x = f2bf(v.x); o.y = f2bf(v.y); o.z = f2bf(v.z); o.w = f2bf(v.w);
  *(ushort4*)(dst + off4) = o;
}

// ---------------- 2. RoPE cos/sin table ----------------
__global__ __launch_bounds__(256) void cs_kernel(float* __restrict__ cst, float* __restrict__ snt) {
  int idx = blockIdx.x * 256 + threadIdx.x;   // 2048*64
  int t = idx >> 6, i = idx & 63;
  float inv = (float)exp(-(double)i * log(10000.0) / 64.0);
  float ang = (float)t * inv;
  cst[idx] = (float)cos((double)ang);
  snt[idx] = (float)sin((double)ang);
}

// ---------------- shared BK=64 GEMM mainloop ----------------
// C[128x128] tile, A[M,K] @ B[N,K]^T bf16. LDS rows = 128 B (8 x 16B chunks),
// XOR-swizzled: phys chunk = logical ^ (row & 7). Staged via global_load_lds
// w/ swizzle folded into the global source address.
__device__ __forceinline__ void gemm_mainloop64(
    const unsigned short* __restrict__ A, const unsigned short* __restrict__ B,
    unsigned short* As, unsigned short* Bs, int m0, int n0, int k0, int ksteps,
    int tid, f32x4 (&acc)[4][4]) {
  int w = tid >> 6, lane = tid & 63;
  int wm = w >> 1, wn = w & 1;
  int q4 = lane >> 4, r = lane & 15;
  f32x4 zero = {0.f, 0.f, 0.f, 0.f};
  #pragma unroll
  for (int mi = 0; mi < 4; mi++)
    #pragma unroll
    for (int ni = 0; ni < 4; ni++) acc[mi][ni] = zero;
  int srow = w * 32 + (lane >> 3);
  int swz = ((lane & 7) ^ (lane >> 3)) * 16;
  const char* Ag = (const char*)(A + (size_t)(m0 + srow) * DM) + swz + k0 * 2;
  const char* Bg = (const char*)(B + (size_t)(n0 + srow) * DM) + swz + k0 * 2;
  unsigned short* Asl = As + w * 2048;
  unsigned short* Bsl = Bs + w * 2048;
  for (int s = 0; s < ksteps; s++) {
    __syncthreads();
    #pragma unroll
    for (int g = 0; g < 4; g++) {
      gload16(Ag + g * (8 * DM * 2), Asl + g * 512);
      gload16(Bg + g * (8 * DM * 2), Bsl + g * 512);
    }
    Ag += 128; Bg += 128;   // advance 64 cols
    __syncthreads();
    #pragma unroll
    for (int kh = 0; kh < 2; kh++) {
      int pcs = ((kh * 4 + q4) ^ (r & 7)) * 8;
      short8 a[4], b[4];
      #pragma unroll
      for (int mi = 0; mi < 4; mi++)
        a[mi] = *(const short8*)(As + (wm * 64 + mi * 16 + r) * 64 + pcs);
      #pragma unroll
      for (int ni = 0; ni < 4; ni++)
        b[ni] = *(const short8*)(Bs + ((ni & 1) * 64 + wn * 32 + (ni >> 1) * 16 + r) * 64 + pcs);
      #pragma unroll
      for (int mi = 0; mi < 4; mi++)
        #pragma unroll
        for (int ni = 0; ni < 4; ni++)
          acc[mi][ni] = __builtin_amdgcn_mfma_f32_16x16x32_bf16(a[mi], b[ni], acc[mi][ni], 0, 0, 0);
    }
  }
}

// ---------------- 3. fused QKV GEMM + RoPE (z<2) / V-transpose (z=2) ----------------
__global__ __launch_bounds__(256, 3) void gemm_qkv_kernel(
    const unsigned short* __restrict__ hsb, const unsigned short* __restrict__ wqb,
    const unsigned short* __restrict__ wkb, const unsigned short* __restrict__ wvb,
    const float* __restrict__ cst, const float* __restrict__ snt,
    unsigned short* __restrict__ qbf, unsigned short* __restrict__ kbf,
    unsigned short* __restrict__ vbT) {
  __shared__ __align__(16) unsigned short LDSBUF[17408];  // As(16KB) + Bs(16KB); vtile reuses all
  unsigned short* As = LDSBUF;
  unsigned short* Bs = LDSBUF + 8192;
  int z = blockIdx.z;
  const unsigned short* B = (z == 0) ? wqb : (z == 1) ? wkb : wvb;
  int m0 = blockIdx.y * 128, n0 = blockIdx.x * 128;
  f32x4 acc[4][4];
  gemm_mainloop64(hsb, B, As, Bs, m0, n0, 0, DM / 64, threadIdx.x, acc);
  int tid = threadIdx.x, w = tid >> 6, lane = tid & 63;
  int wm = w >> 1, wn = w & 1, q4 = lane >> 4, r = lane & 15;
  int h = n0 >> 7;
  if (z < 2) {
    unsigned short* dst = (z == 0) ? qbf : kbf;
    #pragma unroll
    for (int mi = 0; mi < 4; mi++)
      #pragma unroll
      for (int p = 0; p < 2; p++) {
        int d = wn * 32 + p * 16 + r;
        #pragma unroll
        for (int g = 0; g < 4; g++) {
          int t = m0 + wm * 64 + mi * 16 + q4 * 4 + g;
          float c = cst[t * 64 + d], s = snt[t * 64 + d];
          float x0 = acc[mi][2 * p][g], x1 = acc[mi][2 * p + 1][g];
          dst[((size_t)h * T_SEQ + t) * HD + d]      = f2bf(x0 * c - x1 * s);
          dst[((size_t)h * T_SEQ + t) * HD + d + 64] = f2bf(x1 * c + x0 * s);
        }
      }
  } else {
    // transpose C tile (t,d) -> vbT[h][d][t] via LDS (Tpad=136)
    __syncthreads();
    #pragma unroll
    for (int mi = 0; mi < 4; mi++)
      #pragma unroll
      for (int ni = 0; ni < 4; ni++) {
        int c = (ni & 1) * 64 + wn * 32 + (ni >> 1) * 16 + r;
        int tl = wm * 64 + mi * 16 + q4 * 4;
        short4v pv;
        pv[0] = (short)f2bf(acc[mi][ni][0]);
        pv[1] = (short)f2bf(acc[mi][ni][1]);
        pv[2] = (short)f2bf(acc[mi][ni][2]);
        pv[3] = (short)f2bf(acc[mi][ni][3]);
        *(short4v*)(LDSBUF + c * 136 + tl) = pv;
      }
    __syncthreads();
    int d = tid >> 1, th = tid & 1;
    unsigned short* gdst = vbT + ((size_t)h * HD + d) * T_SEQ + m0 + th * 64;
    const unsigned short* lsrc = LDSBUF + d * 136 + th * 64;
    #pragma unroll
    for (int j = 0; j < 8; j++)
      *(short8*)(gdst + j * 8) = *(const short8*)(lsrc + j * 8);
  }
}

// ---------------- 4. flash attention, 64-key super-chunks, cross-iter dbuf ----------------
__device__ __forceinline__ void attn_body(
    int kb, const unsigned short* Kt, const unsigned short* Vt,
    const unsigned short* indv, unsigned short* Psw,
    const short8 (&aq)[4], f32x4 (&o)[8], f32x4& o9, float (&evf)[4],
    int q4, int r) {
  f32x4 zero = {0.f, 0.f, 0.f, 0.f};
  int rsw = (r >> 1) & 3;
  f32x4 s0 = zero, s1 = zero;
  #pragma unroll
  for (int c = 0; c < 4; c++) {
    int pc = ((c * 4 + q4) ^ r) * 8;
    short8 bk0 = *(const short8*)(Kt + r * 128 + pc);
    short8 bk1 = *(const short8*)(Kt + (16 + r) * 128 + pc);
    s0 = __builtin_amdgcn_mfma_f32_16x16x32_bf16(aq[c], bk0, s0, 0, 0, 0);
    s1 = __builtin_amdgcn_mfma_f32_16x16x32_bf16(aq[c], bk1, s1, 0, 0, 0);
  }
  int kg0 = kb + r, kg1 = kb + 16 + r;
  bool keep0 = (kg0 < SB) || (kg0 >= EV);
  bool keep1 = (kg1 < SB) || (kg1 >= EV);
  #pragma unroll
  for (int g = 0; g < 4; g++) {
    float p0 = keep0 ? __expf(fmaf(s0[g], SCALE, -8.0f)) : 0.0f;
    float p1 = keep1 ? __expf(fmaf(s1[g], SCALE, -8.0f)) : 0.0f;
    if (kb == 1216 && kg0 == EV) evf[g] = p0;   // fp32 capture of p(k=1229)
    int row = q4 * 4 + g;
    int psw = (row >> 1) & 3;
    Psw[row * 32 + (((r >> 3) ^ psw) * 8) + (r & 7)]       = f2bf(p0);
    Psw[row * 32 + ((((r >> 3) + 2) ^ psw) * 8) + (r & 7)] = f2bf(p1);
  }
  short8 pa = *(const short8*)(Psw + r * 32 + (q4 ^ rsw) * 8);
  #pragma unroll
  for (int ni = 0; ni < 8; ni++) {
    short8 bv = *(const short8*)(Vt + (ni * 16 + r) * 32 + (q4 ^ rsw) * 8);
    o[ni] = __builtin_amdgcn_mfma_f32_16x16x32_bf16(pa, bv, o[ni], 0, 0, 0);
  }
  short8 bind = *(const short8*)(indv + r * 32 + (q4 ^ rsw) * 8);
  o9 = __builtin_amdgcn_mfma_f32_16x16x32_bf16(pa, bind, o9, 0, 0, 0);
}

__global__ __launch_bounds__(256, 2) void attn_kernel(
    const unsigned short* __restrict__ qbf, const unsigned short* __restrict__ kbf,
    const unsigned short* __restrict__ vbT, unsigned short* __restrict__ atb,
    float* __restrict__ attnf_s, float* __restrict__ Ssum, float* __restrict__ lst) {
  __shared__ __align__(16) unsigned short KtS[2][2][4096];  // [dbuf][sub][32x128u]
  __shared__ __align__(16) unsigned short VtS[2][2][4096];  // [dbuf][sub][128x32u]
  __shared__ __align__(16) unsigned short Ps[4][512];
  __shared__ __align__(16) unsigned short Ind[3 * 512];
  int tid = threadIdx.x, w = tid >> 6, lane = tid & 63;
  int q4 = lane >> 4, r = lane & 15;
  int h = blockIdx.y;
  int qb = blockIdx.x * 64 + w * 16;

  for (int idx = tid; idx < 3 * 512; idx += 256) {
    int v = idx >> 9, n = (idx >> 5) & 15, j = idx & 31;
    float val = 0.f;
    if (n == 0) val = 1.f;
    else if (n == 1) val = (v == 1) ? (j >= 14 ? 1.f : 0.f) : (v == 2 ? 1.f : 0.f);
    Ind[v * 512 + n * 32 + (((j >> 3) ^ ((n >> 1) & 3)) * 8) + (j & 7)] = f2bf(val);
  }

  short8 aq[4];
  {
    const unsigned short* qrow = qbf + ((size_t)h * T_SEQ + qb + r) * HD;
    #pragma unroll
    for (int c = 0; c < 4; c++) aq[c] = *(const short8*)(qrow + c * 32 + q4 * 8);
  }
  f32x4 zero = {0.f, 0.f, 0.f, 0.f};
  f32x4 o[8], o9;
  #pragma unroll
  for (int ni = 0; ni < 8; ni++) o[ni] = zero;
  o9 = zero;
  float evf[4] = {0.f, 0.f, 0.f, 0.f};

  const char* Kbase = (const char*)(kbf + (size_t)h * T_SEQ * HD);
  int krow0 = w * 8 + q4, krow1 = krow0 + 4;
  const char* Kg0 = Kbase + krow0 * 256 + ((r ^ (krow0 & 15)) * 16);
  const char* Kg1 = Kbase + krow1 * 256 + ((r ^ (krow1 & 15)) * 16);
  const char* Vbase = (const char*)(vbT + (size_t)h * HD * T_SEQ);
  int vsrc = ((lane & 3) ^ ((lane >> 3) & 3)) * 16;
  const char* Vg0 = Vbase + (size_t)(w * 32 + (lane >> 2)) * 4096 + vsrc;
  const char* Vg1 = Vg0 + 16 * 4096;

  // prefetch-after-barrier double buffering: issue ci+1 right after the barrier,
  // compute ci from the other buffer; next barrier's vmcnt(0) is the wait.
  auto issue_chunk = [&](int ci, int db) {
    int kb = (ci < 4) ? ci * 64 : 1216 + (ci - 4) * 64;
    gload16(Kg0 + kb * 256,         &KtS[db][0][w * 1024]);
    gload16(Kg1 + kb * 256,         &KtS[db][0][w * 1024 + 512]);
    gload16(Kg0 + (kb + 32) * 256,  &KtS[db][1][w * 1024]);
    gload16(Kg1 + (kb + 32) * 256,  &KtS[db][1][w * 1024 + 512]);
    gload16(Vg0 + kb * 2,           &VtS[db][0][w * 1024]);
    gload16(Vg1 + kb * 2,           &VtS[db][0][w * 1024 + 512]);
    gload16(Vg0 + (kb + 32) * 2,    &VtS[db][1][w * 1024]);
    gload16(Vg1 + (kb + 32) * 2,    &VtS[db][1][w * 1024 + 512]);
  };

  issue_chunk(0, 0);
  for (int ci = 0; ci < 17; ci++) {
    int db = ci & 1;
    int kb = (ci < 4) ? ci * 64 : 1216 + (ci - 4) * 64;
    const unsigned short* indA = Ind + ((ci < 4) ? 0 : (ci == 4) ? 512 : 1024);
    const unsigned short* indB = Ind + ((ci < 4) ? 0 : 1024);
    __syncthreads();
    if (ci < 16) issue_chunk(ci + 1, db ^ 1);
    attn_body(kb,      KtS[db][0], VtS[db][0], indA, &Ps[w][0], aq, o, o9, evf, q4, r);
    attn_body(kb + 32, KtS[db][1], VtS[db][1], indB, &Ps[w][0], aq, o, o9, evf, q4, r);
  }

  float invl[4], srn[4], evn[4];
  #pragma unroll
  for (int g = 0; g < 4; g++) {
    float l  = __shfl(o9[g], lane & 48, 64);
    float sr = __shfl(o9[g], (lane & 48) | 1, 64);
    float ev = __shfl(evf[g], (lane & 48) | 13, 64);
    invl[g] = 1.0f / l;
    srn[g] = sr * invl[g];
    evn[g] = ev * invl[g];
  }
  if (blockIdx.x < (LAST_START / 64)) {
    #pragma unroll
    for (int ni = 0; ni < 8; ni++)
      #pragma unroll
      for (int g = 0; g < 4; g++)
        atb[(size_t)(qb + q4 * 4 + g) * DM + h * HD + ni * 16 + r] = f2bf(o[ni][g] * invl[g]);
  } else {
    #pragma unroll
    for (int ni = 0; ni < 8; ni++)
      #pragma unroll
      for (int g = 0; g < 4; g++)
        attnf_s[(size_t)(qb - LAST_START + q4 * 4 + g) * DM + h * HD + ni * 16 + r] = o[ni][g] * invl[g];
  }
  if (r == 0) {
    #pragma unroll
    for (int g = 0; g < 4; g++) {
      int t = qb + q4 * 4 + g;
      if (t >= LAST_START) Ssum[h * 256 + (t - LAST_START)] = srn[g];
      if (t == T_SEQ - 1) { lst[h * 2] = evn[g]; lst[h * 2 + 1] = srn[g]; }
    }
  }
}

// ---------------- 5. rank-1 eviction fixup (rows >= 1792), bern inlined ----------------
__device__ __forceinline__ void tf_round(uint32_t& x0, uint32_t& x1, int rot) {
  x0 += x1;
  x1 = (x1 << rot) | (x1 >> (32 - rot));
  x1 ^= x0;
}
__device__ __forceinline__ float bern_scale(int hh, const float* lst) {
  const uint32_t k0 = 0u, k1 = 42u, k2 = 0x1BD11BDAu ^ k0 ^ k1;
  uint32_t x0 = (uint32_t)(hh & 7), x1 = (uint32_t)((hh & 7) + 8);
  x0 += k0; x1 += k1;
  tf_round(x0, x1, 13); tf_round(x0, x1, 15); tf_round(x0, x1, 26); tf_round(x0, x1, 6);
  x0 += k1; x1 += k2 + 1u;
  tf_round(x0, x1, 17); tf_round(x0, x1, 29); tf_round(x0, x1, 16); tf_round(x0, x1, 24);
  x0 += k2; x1 += k0 + 2u;
  tf_round(x0, x1, 13); tf_round(x0, x1, 15); tf_round(x0, x1, 26); tf_round(x0, x1, 6);
  x0 += k0; x1 += k1 + 3u;
  tf_round(x0, x1, 17); tf_round(x0, x1, 29); tf_round(x0, x1, 16); tf_round(x0, x1, 24);
  x0 += k1; x1 += k2 + 4u;
  tf_round(x0, x1, 13); tf_round(x0, x1, 15); tf_round(x0, x1, 26); tf_round(x0, x1, 6);
  x0 += k2; x1 += k0 + 5u;
  uint32_t bits = (hh < 8) ? x0 : x1;
  float u = __uint_as_float((bits >> 9) | 0x3f800000u) - 1.0f;
  float evp = lst[hh * 2], srp = lst[hh * 2 + 1];
  float mean = srp * (1.0f / NRECF) + 1e-6f;
  float p = evp / mean;
  p = fminf(fmaxf(p, 0.0f), 1.0f);
  if (!(p == p)) p = 0.0f;
  return (u < p) ? (1.0f / (float)RB) : 0.0f;
}

__global__ __launch_bounds__(256) void fixup_kernel(
    const float* __restrict__ attnf_s, const float* __restrict__ Ssum,
    const float* __restrict__ lst, const unsigned short* __restrict__ vbT,
    unsigned short* __restrict__ atb) {
  int idx = blockIdx.x * 256 + threadIdx.x;   // 256*2048
  int t2 = idx >> 11, n = idx & 2047;
  int h = n >> 7, d = n & 127;
  float bsc = bern_scale(h, lst);
  float v = attnf_s[idx];
  v += Ssum[h * 256 + t2] * bsc * bf2f(vbT[((size_t)h * HD + d) * T_SEQ + EV]);
  atb[(size_t)(t2 + LAST_START) * DM + n] = f2bf(v);
}

// ---------------- 6. output projection GEMM, split-K=2, atomic accumulate ----------------
// d_out is memset to 0 first; exactly two fp32 contributions per element
// (commutative -> deterministic). nan_to_num is identity on this finite data.
__global__ __launch_bounds__(256, 2) void gemm_out_kernel(
    const unsigned short* __restrict__ atb, const unsigned short* __restrict__ wob,
    float* __restrict__ out) {
  __shared__ __align__(16) unsigned short LDSBUF[16384];
  unsigned short* As = LDSBUF;
  unsigned short* Bs = LDSBUF + 8192;
  int m0 = blockIdx.y * 128, n0 = blockIdx.x * 128;
  int kz = blockIdx.z;
  f32x4 acc[4][4];
  gemm_mainloop64(atb, wob, As, Bs, m0, n0, kz * 1024, 16, threadIdx.x, acc);
  int tid = threadIdx.x, w = tid >> 6, lane = tid & 63;
  int wm = w >> 1, wn = w & 1, q4 = lane >> 4, r = lane & 15;
  #pragma unroll
  for (int mi = 0; mi < 4; mi++)
    #pragma unroll
    for (int ni = 0; ni < 4; ni++) {
      int c = n0 + (ni & 1) * 64 + wn * 32 + (ni >> 1) * 16 + r;
      #pragma unroll
      for (int g = 0; g < 4; g++) {
        int t = m0 + wm * 64 + mi * 16 + q4 * 4 + g;
        atomicAdd(&out[(size_t)t * DM + c], acc[mi][ni][g]);
      }
    }
}

// ---------------- launch ----------------
extern "C" void kernel_launch(void* const* d_in, const int* in_sizes, int n_in,
                              void* d_out, int out_size, void* d_ws, size_t ws_size,
                              hipStream_t stream) {
  const float* hs = (const float*)d_in[0];
  const float* Wq = (const float*)d_in[1];
  const float* Wk = (const float*)d_in[2];
  const float* Wv = (const float*)d_in[3];
  const float* Wo = (const float*)d_in[4];
  char* ws = (char*)d_ws;
  const size_t MB = 1024 * 1024;
  unsigned short* hsb = (unsigned short*)(ws + 0);         // 8 MB
  unsigned short* wqb = (unsigned short*)(ws + 8 * MB);    // 8 MB
  unsigned short* wkb = (unsigned short*)(ws + 16 * MB);   // 8 MB
  unsigned short* wvb = (unsigned short*)(ws + 24 * MB);   // 8 MB
  unsigned short* wob = (unsigned short*)(ws + 32 * MB);   // 8 MB
  unsigned short* qbf = (unsigned short*)(ws + 40 * MB);   // 8 MB
  unsigned short* kbf = (unsigned short*)(ws + 48 * MB);   // 8 MB
  unsigned short* vbT = (unsigned short*)(ws + 56 * MB);   // 8 MB
  unsigned short* atb = (unsigned short*)(ws + 64 * MB);   // 8 MB
  float* attnf_s = (float*)(ws + 72 * MB);                 // 2 MB (rows 1792..2047)
  float* cst = (float*)(ws + 74 * MB);                     // 512 KB
  float* snt = (float*)(ws + 74 * MB + 524288);            // 512 KB
  float* Ssum = (float*)(ws + 75 * MB);                    // 16 KB
  float* lst = (float*)(ws + 75 * MB + 16384);             // 128 B

  hipMemsetAsync(d_out, 0, (size_t)out_size * sizeof(float), stream);
  cvt_kernel<<<20480, 256, 0, stream>>>(hs, Wq, Wk, Wv, Wo, hsb, wqb, wkb, wvb, wob);
  cs_kernel<<<512, 256, 0, stream>>>(cst, snt);
  gemm_qkv_kernel<<<dim3(16, 16, 3), 256, 0, stream>>>(hsb, wqb, wkb, wvb, cst, snt, qbf, kbf, vbT);
  attn_kernel<<<dim3(32, 16), 256, 0, stream>>>(qbf, kbf, vbT, atb, attnf_s, Ssum, lst);
  fixup_kernel<<<2048, 256, 0, stream>>>(attnf_s, Ssum, lst, vbT, atb);
  gemm_out_kernel<<<dim3(16, 16, 2), 256, 0, stream>>>(atb, wob, (float*)d_out);
}

// Round 5
// 248.226 us; speedup vs baseline: 1.0491x; 1.0491x over previous
//
#include <hip/hip_runtime.h>
#include <stdint.h>

// ---------------- constants ----------------
#define T_SEQ 2048
#define DM    2048
#define NH    16
#define HD    128
#define SB    204          // int(0.1*2048)
#define EV    1229         // 2048 - 819
#define RB    819          // int(0.4*2048)
#define NRECF 818.0f       // 2048 - (EV+1)
#define LAST_START 1792    // (2047//256)*256
#define SCALE 0.08838834764831845f  // 1/sqrt(128)

typedef __attribute__((ext_vector_type(8))) short short8;
typedef __attribute__((ext_vector_type(4))) short short4v;
typedef __attribute__((ext_vector_type(4))) float f32x4;

__device__ __forceinline__ unsigned short f2bf(float f) {
  uint32_t u = __float_as_uint(f);
  u += 0x7fffu + ((u >> 16) & 1u);   // RNE
  return (unsigned short)(u >> 16);
}
__device__ __forceinline__ float bf2f(unsigned short s) {
  return __uint_as_float(((uint32_t)s) << 16);
}
__device__ __forceinline__ void gload16(const void* g, void* l) {
  __builtin_amdgcn_global_load_lds((const __attribute__((address_space(1))) void*)g,
                                   (__attribute__((address_space(3))) void*)l,
                                   16, 0, 0);
}
__device__ __forceinline__ float n2n(float v) {
  if (isnan(v)) return 0.0f;
  if (isinf(v)) return v > 0.0f ? 10000.0f : -10000.0f;
  return v;
}

// ---------------- 1. fp32 -> bf16 conversions + RoPE table (fused) ----------------
__global__ __launch_bounds__(256) void cvt_kernel(
    const float* __restrict__ hs, const float* __restrict__ wq,
    const float* __restrict__ wk, const float* __restrict__ wv,
    const float* __restrict__ wo, unsigned short* __restrict__ hsb,
    unsigned short* __restrict__ wqb, unsigned short* __restrict__ wkb,
    unsigned short* __restrict__ wvb, unsigned short* __restrict__ wob,
    float* __restrict__ cst, float* __restrict__ snt) {
  if (blockIdx.x >= 20480) {   // RoPE cos/sin table tail blocks
    int idx = (blockIdx.x - 20480) * 256 + threadIdx.x;   // 2048*64
    int t = idx >> 6, i = idx & 63;
    float inv = (float)exp(-(double)i * log(10000.0) / 64.0);
    float ang = (float)t * inv;
    cst[idx] = (float)cos((double)ang);
    snt[idx] = (float)sin((double)ang);
    return;
  }
  int gid = blockIdx.x * 256 + threadIdx.x;
  int region = gid >> 20;
  int off4 = (gid & 1048575) * 4;
  const float* src; unsigned short* dst;
  switch (region) {
    case 0: src = hs; dst = hsb; break;
    case 1: src = wq; dst = wqb; break;
    case 2: src = wk; dst = wkb; break;
    case 3: src = wv; dst = wvb; break;
    default: src = wo; dst = wob; break;
  }
  float4 v = *(const float4*)(src + off4);
  if (region == 0) { v.x = n2n(v.x); v.y = n2n(v.y); v.z = n2n(v.z); v.w = n2n(v.w); }
  ushort4 o;
  o.x = f2bf(v.x); o.y = f2bf(v.y); o.z = f2bf(v.z); o.w = f2bf(v.w);
  *(ushort4*)(dst + off4) = o;
}

// ---------------- shared BK=64 GEMM mainloop, cross-iter double-buffered ----------------
// C[128x128] tile, A[M,K] @ B[N,K]^T bf16. LDS rows = 128 B (8 x 16B chunks),
// XOR-swizzled: phys chunk = logical ^ (row & 7), folded into global src addr.
// Prefetch-after-barrier: issue iter s+1's global_load_lds right after barrier s,
// compute iter s from the other buffer; next barrier's vmcnt(0) is the wait.
__device__ __forceinline__ void gemm_mainloop64_db(
    const unsigned short* __restrict__ A, const unsigned short* __restrict__ B,
    unsigned short* LDSBUF,   // 32768 shorts: As0|Bs0|As1|Bs1 (8192 each)
    int m0, int n0, int k0, int ksteps, int tid, f32x4 (&acc)[4][4]) {
  int w = tid >> 6, lane = tid & 63;
  int wm = w >> 1, wn = w & 1;
  int q4 = lane >> 4, r = lane & 15;
  f32x4 zero = {0.f, 0.f, 0.f, 0.f};
  #pragma unroll
  for (int mi = 0; mi < 4; mi++)
    #pragma unroll
    for (int ni = 0; ni < 4; ni++) acc[mi][ni] = zero;
  int srow = w * 32 + (lane >> 3);
  int swz = ((lane & 7) ^ (lane >> 3)) * 16;
  const char* Ag = (const char*)(A + (size_t)(m0 + srow) * DM) + swz + k0 * 2;
  const char* Bg = (const char*)(B + (size_t)(n0 + srow) * DM) + swz + k0 * 2;
  unsigned short* AsB[2] = {LDSBUF + w * 2048, LDSBUF + 16384 + w * 2048};
  unsigned short* BsB[2] = {LDSBUF + 8192 + w * 2048, LDSBUF + 24576 + w * 2048};
  // prefetch iter 0 into buf 0
  #pragma unroll
  for (int g = 0; g < 4; g++) {
    gload16(Ag + g * (8 * DM * 2), AsB[0] + g * 512);
    gload16(Bg + g * (8 * DM * 2), BsB[0] + g * 512);
  }
  for (int s = 0; s < ksteps; s++) {
    int db = s & 1;
    __syncthreads();   // drains prefetch for iter s; fences prior reads of buf db
    if (s + 1 < ksteps) {
      #pragma unroll
      for (int g = 0; g < 4; g++) {
        gload16(Ag + 128 + g * (8 * DM * 2), AsB[db ^ 1] + g * 512);
        gload16(Bg + 128 + g * (8 * DM * 2), BsB[db ^ 1] + g * 512);
      }
    }
    Ag += 128; Bg += 128;   // advance 64 cols
    const unsigned short* As = LDSBUF + (db ? 16384 : 0);
    const unsigned short* Bs = LDSBUF + (db ? 24576 : 8192);
    #pragma unroll
    for (int kh = 0; kh < 2; kh++) {
      int pcs = ((kh * 4 + q4) ^ (r & 7)) * 8;
      short8 a[4], b[4];
      #pragma unroll
      for (int mi = 0; mi < 4; mi++)
        a[mi] = *(const short8*)(As + (wm * 64 + mi * 16 + r) * 64 + pcs);
      #pragma unroll
      for (int ni = 0; ni < 4; ni++)
        b[ni] = *(const short8*)(Bs + ((ni & 1) * 64 + wn * 32 + (ni >> 1) * 16 + r) * 64 + pcs);
      #pragma unroll
      for (int mi = 0; mi < 4; mi++)
        #pragma unroll
        for (int ni = 0; ni < 4; ni++)
          acc[mi][ni] = __builtin_amdgcn_mfma_f32_16x16x32_bf16(a[mi], b[ni], acc[mi][ni], 0, 0, 0);
    }
  }
}

// ---------------- 3. fused QKV GEMM + RoPE (z<2) / V-transpose (z=2) ----------------
__global__ __launch_bounds__(256, 2) void gemm_qkv_kernel(
    const unsigned short* __restrict__ hsb, const unsigned short* __restrict__ wqb,
    const unsigned short* __restrict__ wkb, const unsigned short* __restrict__ wvb,
    const float* __restrict__ cst, const float* __restrict__ snt,
    unsigned short* __restrict__ qbf, unsigned short* __restrict__ kbf,
    unsigned short* __restrict__ vbT) {
  __shared__ __align__(16) unsigned short LDSBUF[32768];  // 64 KB dbuf; vtile reuses
  int z = blockIdx.z;
  const unsigned short* B = (z == 0) ? wqb : (z == 1) ? wkb : wvb;
  int m0 = blockIdx.y * 128, n0 = blockIdx.x * 128;
  f32x4 acc[4][4];
  gemm_mainloop64_db(hsb, B, LDSBUF, m0, n0, 0, DM / 64, threadIdx.x, acc);
  int tid = threadIdx.x, w = tid >> 6, lane = tid & 63;
  int wm = w >> 1, wn = w & 1, q4 = lane >> 4, r = lane & 15;
  int h = n0 >> 7;
  if (z < 2) {
    unsigned short* dst = (z == 0) ? qbf : kbf;
    #pragma unroll
    for (int mi = 0; mi < 4; mi++)
      #pragma unroll
      for (int p = 0; p < 2; p++) {
        int d = wn * 32 + p * 16 + r;
        #pragma unroll
        for (int g = 0; g < 4; g++) {
          int t = m0 + wm * 64 + mi * 16 + q4 * 4 + g;
          float c = cst[t * 64 + d], s = snt[t * 64 + d];
          float x0 = acc[mi][2 * p][g], x1 = acc[mi][2 * p + 1][g];
          dst[((size_t)h * T_SEQ + t) * HD + d]      = f2bf(x0 * c - x1 * s);
          dst[((size_t)h * T_SEQ + t) * HD + d + 64] = f2bf(x1 * c + x0 * s);
        }
      }
  } else {
    // transpose C tile (t,d) -> vbT[h][d][t] via LDS (Tpad=136)
    __syncthreads();
    #pragma unroll
    for (int mi = 0; mi < 4; mi++)
      #pragma unroll
      for (int ni = 0; ni < 4; ni++) {
        int c = (ni & 1) * 64 + wn * 32 + (ni >> 1) * 16 + r;
        int tl = wm * 64 + mi * 16 + q4 * 4;
        short4v pv;
        pv[0] = (short)f2bf(acc[mi][ni][0]);
        pv[1] = (short)f2bf(acc[mi][ni][1]);
        pv[2] = (short)f2bf(acc[mi][ni][2]);
        pv[3] = (short)f2bf(acc[mi][ni][3]);
        *(short4v*)(LDSBUF + c * 136 + tl) = pv;
      }
    __syncthreads();
    int d = tid >> 1, th = tid & 1;
    unsigned short* gdst = vbT + ((size_t)h * HD + d) * T_SEQ + m0 + th * 64;
    const unsigned short* lsrc = LDSBUF + d * 136 + th * 64;
    #pragma unroll
    for (int j = 0; j < 8; j++)
      *(short8*)(gdst + j * 8) = *(const short8*)(lsrc + j * 8);
  }
}

// ---------------- 4. flash attention, 64-key super-chunks, cross-iter dbuf ----------------
__device__ __forceinline__ void attn_body(
    int kb, const unsigned short* Kt, const unsigned short* Vt,
    const unsigned short* indv, unsigned short* Psw,
    const short8 (&aq)[4], f32x4 (&o)[8], f32x4& o9, float (&evf)[4],
    int q4, int r) {
  f32x4 zero = {0.f, 0.f, 0.f, 0.f};
  int rsw = (r >> 1) & 3;
  f32x4 s0 = zero, s1 = zero;
  #pragma unroll
  for (int c = 0; c < 4; c++) {
    int pc = ((c * 4 + q4) ^ r) * 8;
    short8 bk0 = *(const short8*)(Kt + r * 128 + pc);
    short8 bk1 = *(const short8*)(Kt + (16 + r) * 128 + pc);
    s0 = __builtin_amdgcn_mfma_f32_16x16x32_bf16(aq[c], bk0, s0, 0, 0, 0);
    s1 = __builtin_amdgcn_mfma_f32_16x16x32_bf16(aq[c], bk1, s1, 0, 0, 0);
  }
  int kg0 = kb + r, kg1 = kb + 16 + r;
  bool keep0 = (kg0 < SB) || (kg0 >= EV);
  bool keep1 = (kg1 < SB) || (kg1 >= EV);
  #pragma unroll
  for (int g = 0; g < 4; g++) {
    float p0 = keep0 ? __expf(fmaf(s0[g], SCALE, -8.0f)) : 0.0f;
    float p1 = keep1 ? __expf(fmaf(s1[g], SCALE, -8.0f)) : 0.0f;
    if (kb == 1216 && kg0 == EV) evf[g] = p0;   // fp32 capture of p(k=1229)
    int row = q4 * 4 + g;
    int psw = (row >> 1) & 3;
    Psw[row * 32 + (((r >> 3) ^ psw) * 8) + (r & 7)]       = f2bf(p0);
    Psw[row * 32 + ((((r >> 3) + 2) ^ psw) * 8) + (r & 7)] = f2bf(p1);
  }
  short8 pa = *(const short8*)(Psw + r * 32 + (q4 ^ rsw) * 8);
  #pragma unroll
  for (int ni = 0; ni < 8; ni++) {
    short8 bv = *(const short8*)(Vt + (ni * 16 + r) * 32 + (q4 ^ rsw) * 8);
    o[ni] = __builtin_amdgcn_mfma_f32_16x16x32_bf16(pa, bv, o[ni], 0, 0, 0);
  }
  short8 bind = *(const short8*)(indv + r * 32 + (q4 ^ rsw) * 8);
  o9 = __builtin_amdgcn_mfma_f32_16x16x32_bf16(pa, bind, o9, 0, 0, 0);
}

__global__ __launch_bounds__(256, 2) void attn_kernel(
    const unsigned short* __restrict__ qbf, const unsigned short* __restrict__ kbf,
    const unsigned short* __restrict__ vbT, unsigned short* __restrict__ atb,
    float* __restrict__ attnf_s, float* __restrict__ Ssum, float* __restrict__ lst) {
  __shared__ __align__(16) unsigned short KtS[2][2][4096];  // [dbuf][sub][32x128u]
  __shared__ __align__(16) unsigned short VtS[2][2][4096];  // [dbuf][sub][128x32u]
  __shared__ __align__(16) unsigned short Ps[4][512];
  __shared__ __align__(16) unsigned short Ind[3 * 512];
  int tid = threadIdx.x, w = tid >> 6, lane = tid & 63;
  int q4 = lane >> 4, r = lane & 15;
  int h = blockIdx.y;
  int qb = blockIdx.x * 64 + w * 16;

  for (int idx = tid; idx < 3 * 512; idx += 256) {
    int v = idx >> 9, n = (idx >> 5) & 15, j = idx & 31;
    float val = 0.f;
    if (n == 0) val = 1.f;
    else if (n == 1) val = (v == 1) ? (j >= 14 ? 1.f : 0.f) : (v == 2 ? 1.f : 0.f);
    Ind[v * 512 + n * 32 + (((j >> 3) ^ ((n >> 1) & 3)) * 8) + (j & 7)] = f2bf(val);
  }

  short8 aq[4];
  {
    const unsigned short* qrow = qbf + ((size_t)h * T_SEQ + qb + r) * HD;
    #pragma unroll
    for (int c = 0; c < 4; c++) aq[c] = *(const short8*)(qrow + c * 32 + q4 * 8);
  }
  f32x4 zero = {0.f, 0.f, 0.f, 0.f};
  f32x4 o[8], o9;
  #pragma unroll
  for (int ni = 0; ni < 8; ni++) o[ni] = zero;
  o9 = zero;
  float evf[4] = {0.f, 0.f, 0.f, 0.f};

  const char* Kbase = (const char*)(kbf + (size_t)h * T_SEQ * HD);
  int krow0 = w * 8 + q4, krow1 = krow0 + 4;
  const char* Kg0 = Kbase + krow0 * 256 + ((r ^ (krow0 & 15)) * 16);
  const char* Kg1 = Kbase + krow1 * 256 + ((r ^ (krow1 & 15)) * 16);
  const char* Vbase = (const char*)(vbT + (size_t)h * HD * T_SEQ);
  int vsrc = ((lane & 3) ^ ((lane >> 3) & 3)) * 16;
  const char* Vg0 = Vbase + (size_t)(w * 32 + (lane >> 2)) * 4096 + vsrc;
  const char* Vg1 = Vg0 + 16 * 4096;

  auto issue_chunk = [&](int ci, int db) {
    int kb = (ci < 4) ? ci * 64 : 1216 + (ci - 4) * 64;
    gload16(Kg0 + kb * 256,         &KtS[db][0][w * 1024]);
    gload16(Kg1 + kb * 256,         &KtS[db][0][w * 1024 + 512]);
    gload16(Kg0 + (kb + 32) * 256,  &KtS[db][1][w * 1024]);
    gload16(Kg1 + (kb + 32) * 256,  &KtS[db][1][w * 1024 + 512]);
    gload16(Vg0 + kb * 2,           &VtS[db][0][w * 1024]);
    gload16(Vg1 + kb * 2,           &VtS[db][0][w * 1024 + 512]);
    gload16(Vg0 + (kb + 32) * 2,    &VtS[db][1][w * 1024]);
    gload16(Vg1 + (kb + 32) * 2,    &VtS[db][1][w * 1024 + 512]);
  };

  issue_chunk(0, 0);
  for (int ci = 0; ci < 17; ci++) {
    int db = ci & 1;
    int kb = (ci < 4) ? ci * 64 : 1216 + (ci - 4) * 64;
    const unsigned short* indA = Ind + ((ci < 4) ? 0 : (ci == 4) ? 512 : 1024);
    const unsigned short* indB = Ind + ((ci < 4) ? 0 : 1024);
    __syncthreads();
    if (ci < 16) issue_chunk(ci + 1, db ^ 1);
    attn_body(kb,      KtS[db][0], VtS[db][0], indA, &Ps[w][0], aq, o, o9, evf, q4, r);
    attn_body(kb + 32, KtS[db][1], VtS[db][1], indB, &Ps[w][0], aq, o, o9, evf, q4, r);
  }

  float invl[4], srn[4], evn[4];
  #pragma unroll
  for (int g = 0; g < 4; g++) {
    float l  = __shfl(o9[g], lane & 48, 64);
    float sr = __shfl(o9[g], (lane & 48) | 1, 64);
    float ev = __shfl(evf[g], (lane & 48) | 13, 64);
    invl[g] = 1.0f / l;
    srn[g] = sr * invl[g];
    evn[g] = ev * invl[g];
  }
  if (blockIdx.x < (LAST_START / 64)) {
    #pragma unroll
    for (int ni = 0; ni < 8; ni++)
      #pragma unroll
      for (int g = 0; g < 4; g++)
        atb[(size_t)(qb + q4 * 4 + g) * DM + h * HD + ni * 16 + r] = f2bf(o[ni][g] * invl[g]);
  } else {
    #pragma unroll
    for (int ni = 0; ni < 8; ni++)
      #pragma unroll
      for (int g = 0; g < 4; g++)
        attnf_s[(size_t)(qb - LAST_START + q4 * 4 + g) * DM + h * HD + ni * 16 + r] = o[ni][g] * invl[g];
  }
  if (r == 0) {
    #pragma unroll
    for (int g = 0; g < 4; g++) {
      int t = qb + q4 * 4 + g;
      if (t >= LAST_START) Ssum[h * 256 + (t - LAST_START)] = srn[g];
      if (t == T_SEQ - 1) { lst[h * 2] = evn[g]; lst[h * 2 + 1] = srn[g]; }
    }
  }
}

// ---------------- 5. rank-1 eviction fixup (rows >= 1792), bern inlined ----------------
__device__ __forceinline__ void tf_round(uint32_t& x0, uint32_t& x1, int rot) {
  x0 += x1;
  x1 = (x1 << rot) | (x1 >> (32 - rot));
  x1 ^= x0;
}
__device__ __forceinline__ float bern_scale(int hh, const float* lst) {
  const uint32_t k0 = 0u, k1 = 42u, k2 = 0x1BD11BDAu ^ k0 ^ k1;
  uint32_t x0 = (uint32_t)(hh & 7), x1 = (uint32_t)((hh & 7) + 8);
  x0 += k0; x1 += k1;
  tf_round(x0, x1, 13); tf_round(x0, x1, 15); tf_round(x0, x1, 26); tf_round(x0, x1, 6);
  x0 += k1; x1 += k2 + 1u;
  tf_round(x0, x1, 17); tf_round(x0, x1, 29); tf_round(x0, x1, 16); tf_round(x0, x1, 24);
  x0 += k2; x1 += k0 + 2u;
  tf_round(x0, x1, 13); tf_round(x0, x1, 15); tf_round(x0, x1, 26); tf_round(x0, x1, 6);
  x0 += k0; x1 += k1 + 3u;
  tf_round(x0, x1, 17); tf_round(x0, x1, 29); tf_round(x0, x1, 16); tf_round(x0, x1, 24);
  x0 += k1; x1 += k2 + 4u;
  tf_round(x0, x1, 13); tf_round(x0, x1, 15); tf_round(x0, x1, 26); tf_round(x0, x1, 6);
  x0 += k2; x1 += k0 + 5u;
  uint32_t bits = (hh < 8) ? x0 : x1;
  float u = __uint_as_float((bits >> 9) | 0x3f800000u) - 1.0f;
  float evp = lst[hh * 2], srp = lst[hh * 2 + 1];
  float mean = srp * (1.0f / NRECF) + 1e-6f;
  float p = evp / mean;
  p = fminf(fmaxf(p, 0.0f), 1.0f);
  if (!(p == p)) p = 0.0f;
  return (u < p) ? (1.0f / (float)RB) : 0.0f;
}

__global__ __launch_bounds__(256) void fixup_kernel(
    const float* __restrict__ attnf_s, const float* __restrict__ Ssum,
    const float* __restrict__ lst, const unsigned short* __restrict__ vbT,
    unsigned short* __restrict__ atb) {
  int idx = blockIdx.x * 256 + threadIdx.x;   // 256*2048
  int t2 = idx >> 11, n = idx & 2047;
  int h = n >> 7, d = n & 127;
  float bsc = bern_scale(h, lst);
  float v = attnf_s[idx];
  v += Ssum[h * 256 + t2] * bsc * bf2f(vbT[((size_t)h * HD + d) * T_SEQ + EV]);
  atb[(size_t)(t2 + LAST_START) * DM + n] = f2bf(v);
}

// ---------------- 6. output projection GEMM, split-K=2, partials ----------------
__global__ __launch_bounds__(256, 2) void gemm_out_kernel(
    const unsigned short* __restrict__ atb, const unsigned short* __restrict__ wob,
    float* __restrict__ part0, float* __restrict__ part1) {
  __shared__ __align__(16) unsigned short LDSBUF[32768];
  int m0 = blockIdx.y * 128, n0 = blockIdx.x * 128;
  int kz = blockIdx.z;
  float* part = kz ? part1 : part0;
  f32x4 acc[4][4];
  gemm_mainloop64_db(atb, wob, LDSBUF, m0, n0, kz * 1024, 16, threadIdx.x, acc);
  int tid = threadIdx.x, w = tid >> 6, lane = tid & 63;
  int wm = w >> 1, wn = w & 1, q4 = lane >> 4, r = lane & 15;
  #pragma unroll
  for (int mi = 0; mi < 4; mi++)
    #pragma unroll
    for (int ni = 0; ni < 4; ni++) {
      int c = n0 + (ni & 1) * 64 + wn * 32 + (ni >> 1) * 16 + r;
      #pragma unroll
      for (int g = 0; g < 4; g++) {
        int t = m0 + wm * 64 + mi * 16 + q4 * 4 + g;
        part[(size_t)t * DM + c] = acc[mi][ni][g];
      }
    }
}

// ---------------- 7. partial add + nan_to_num ----------------
__global__ __launch_bounds__(256) void add_kernel(
    const float* __restrict__ p0, const float* __restrict__ p1, float* __restrict__ out) {
  int i4 = (blockIdx.x * 256 + threadIdx.x) * 4;
  float4 a = *(const float4*)(p0 + i4);
  float4 b = *(const float4*)(p1 + i4);
  float4 o;
  o.x = n2n(a.x + b.x); o.y = n2n(a.y + b.y);
  o.z = n2n(a.z + b.z); o.w = n2n(a.w + b.w);
  *(float4*)(out + i4) = o;
}

// ---------------- launch ----------------
extern "C" void kernel_launch(void* const* d_in, const int* in_sizes, int n_in,
                              void* d_out, int out_size, void* d_ws, size_t ws_size,
                              hipStream_t stream) {
  const float* hs = (const float*)d_in[0];
  const float* Wq = (const float*)d_in[1];
  const float* Wk = (const float*)d_in[2];
  const float* Wv = (const float*)d_in[3];
  const float* Wo = (const float*)d_in[4];
  char* ws = (char*)d_ws;
  const size_t MB = 1024 * 1024;
  unsigned short* hsb = (unsigned short*)(ws + 0);         // 8 MB
  unsigned short* wqb = (unsigned short*)(ws + 8 * MB);    // 8 MB
  unsigned short* wkb = (unsigned short*)(ws + 16 * MB);   // 8 MB
  unsigned short* wvb = (unsigned short*)(ws + 24 * MB);   // 8 MB
  unsigned short* wob = (unsigned short*)(ws + 32 * MB);   // 8 MB
  unsigned short* qbf = (unsigned short*)(ws + 40 * MB);   // 8 MB
  unsigned short* kbf = (unsigned short*)(ws + 48 * MB);   // 8 MB
  unsigned short* vbT = (unsigned short*)(ws + 56 * MB);   // 8 MB
  unsigned short* atb = (unsigned short*)(ws + 64 * MB);   // 8 MB
  float* attnf_s = (float*)(ws + 72 * MB);                 // 2 MB (rows 1792..2047)
  float* part0 = (float*)(ws + 74 * MB);                   // 16 MB
  float* part1 = (float*)(ws + 90 * MB);                   // 16 MB
  float* cst = (float*)(ws + 106 * MB);                    // 512 KB
  float* snt = (float*)(ws + 106 * MB + 524288);           // 512 KB
  float* Ssum = (float*)(ws + 107 * MB);                   // 16 KB
  float* lst = (float*)(ws + 107 * MB + 16384);            // 128 B

  cvt_kernel<<<20992, 256, 0, stream>>>(hs, Wq, Wk, Wv, Wo, hsb, wqb, wkb, wvb, wob, cst, snt);
  gemm_qkv_kernel<<<dim3(16, 16, 3), 256, 0, stream>>>(hsb, wqb, wkb, wvb, cst, snt, qbf, kbf, vbT);
  attn_kernel<<<dim3(32, 16), 256, 0, stream>>>(qbf, kbf, vbT, atb, attnf_s, Ssum, lst);
  fixup_kernel<<<2048, 256, 0, stream>>>(attnf_s, Ssum, lst, vbT, atb);
  gemm_out_kernel<<<dim3(16, 16, 2), 256, 0, stream>>>(atb, wob, part0, part1);
  add_kernel<<<4096, 256, 0, stream>>>(part0, part1, (float*)d_out);
}

// Round 6
// 242.487 us; speedup vs baseline: 1.0740x; 1.0237x over previous
//
#include <hip/hip_runtime.h>
#include <stdint.h>

// ---------------- constants ----------------
#define T_SEQ 2048
#define DM    2048
#define NH    16
#define HD    128
#define SB    204          // int(0.1*2048)
#define EV    1229         // 2048 - 819
#define RB    819          // int(0.4*2048)
#define NRECF 818.0f       // 2048 - (EV+1)
#define LAST_START 1792    // (2047//256)*256
#define SCALE 0.08838834764831845f  // 1/sqrt(128)

typedef __attribute__((ext_vector_type(8))) short short8;
typedef __attribute__((ext_vector_type(4))) short short4v;
typedef __attribute__((ext_vector_type(4))) float f32x4;

__device__ __forceinline__ unsigned short f2bf(float f) {
  uint32_t u = __float_as_uint(f);
  u += 0x7fffu + ((u >> 16) & 1u);   // RNE
  return (unsigned short)(u >> 16);
}
__device__ __forceinline__ float bf2f(unsigned short s) {
  return __uint_as_float(((uint32_t)s) << 16);
}
__device__ __forceinline__ void gload16(const void* g, void* l) {
  __builtin_amdgcn_global_load_lds((const __attribute__((address_space(1))) void*)g,
                                   (__attribute__((address_space(3))) void*)l,
                                   16, 0, 0);
}
__device__ __forceinline__ float n2n(float v) {
  if (isnan(v)) return 0.0f;
  if (isinf(v)) return v > 0.0f ? 10000.0f : -10000.0f;
  return v;
}

// ---------------- 1. fp32 -> bf16 conversions + RoPE table (fused) ----------------
__global__ __launch_bounds__(256) void cvt_kernel(
    const float* __restrict__ hs, const float* __restrict__ wq,
    const float* __restrict__ wk, const float* __restrict__ wv,
    const float* __restrict__ wo, unsigned short* __restrict__ hsb,
    unsigned short* __restrict__ wqb, unsigned short* __restrict__ wkb,
    unsigned short* __restrict__ wvb, unsigned short* __restrict__ wob,
    float* __restrict__ cst, float* __restrict__ snt) {
  if (blockIdx.x >= 20480) {   // RoPE cos/sin table tail blocks
    int idx = (blockIdx.x - 20480) * 256 + threadIdx.x;   // 2048*64
    int t = idx >> 6, i = idx & 63;
    float inv = (float)exp(-(double)i * log(10000.0) / 64.0);
    float ang = (float)t * inv;
    cst[idx] = (float)cos((double)ang);
    snt[idx] = (float)sin((double)ang);
    return;
  }
  int gid = blockIdx.x * 256 + threadIdx.x;
  int region = gid >> 20;
  int off4 = (gid & 1048575) * 4;
  const float* src; unsigned short* dst;
  switch (region) {
    case 0: src = hs; dst = hsb; break;
    case 1: src = wq; dst = wqb; break;
    case 2: src = wk; dst = wkb; break;
    case 3: src = wv; dst = wvb; break;
    default: src = wo; dst = wob; break;
  }
  float4 v = *(const float4*)(src + off4);
  if (region == 0) { v.x = n2n(v.x); v.y = n2n(v.y); v.z = n2n(v.z); v.w = n2n(v.w); }
  ushort4 o;
  o.x = f2bf(v.x); o.y = f2bf(v.y); o.z = f2bf(v.z); o.w = f2bf(v.w);
  *(ushort4*)(dst + off4) = o;
}

// ---------------- shared BK=64 GEMM mainloop (single-buffer, proven round-4) ----------------
// C[128x128] tile, A[M,K] @ B[N,K]^T bf16. LDS rows = 128 B (8 x 16B chunks),
// XOR-swizzled: phys chunk = logical ^ (row & 7), folded into global src addr.
__device__ __forceinline__ void gemm_mainloop64(
    const unsigned short* __restrict__ A, const unsigned short* __restrict__ B,
    unsigned short* As, unsigned short* Bs, int m0, int n0, int k0, int ksteps,
    int tid, f32x4 (&acc)[4][4]) {
  int w = tid >> 6, lane = tid & 63;
  int wm = w >> 1, wn = w & 1;
  int q4 = lane >> 4, r = lane & 15;
  f32x4 zero = {0.f, 0.f, 0.f, 0.f};
  #pragma unroll
  for (int mi = 0; mi < 4; mi++)
    #pragma unroll
    for (int ni = 0; ni < 4; ni++) acc[mi][ni] = zero;
  int srow = w * 32 + (lane >> 3);
  int swz = ((lane & 7) ^ (lane >> 3)) * 16;
  const char* Ag = (const char*)(A + (size_t)(m0 + srow) * DM) + swz + k0 * 2;
  const char* Bg = (const char*)(B + (size_t)(n0 + srow) * DM) + swz + k0 * 2;
  unsigned short* Asl = As + w * 2048;
  unsigned short* Bsl = Bs + w * 2048;
  for (int s = 0; s < ksteps; s++) {
    __syncthreads();
    #pragma unroll
    for (int g = 0; g < 4; g++) {
      gload16(Ag + g * (8 * DM * 2), Asl + g * 512);
      gload16(Bg + g * (8 * DM * 2), Bsl + g * 512);
    }
    Ag += 128; Bg += 128;   // advance 64 cols
    __syncthreads();
    #pragma unroll
    for (int kh = 0; kh < 2; kh++) {
      int pcs = ((kh * 4 + q4) ^ (r & 7)) * 8;
      short8 a[4], b[4];
      #pragma unroll
      for (int mi = 0; mi < 4; mi++)
        a[mi] = *(const short8*)(As + (wm * 64 + mi * 16 + r) * 64 + pcs);
      #pragma unroll
      for (int ni = 0; ni < 4; ni++)
        b[ni] = *(const short8*)(Bs + ((ni & 1) * 64 + wn * 32 + (ni >> 1) * 16 + r) * 64 + pcs);
      #pragma unroll
      for (int mi = 0; mi < 4; mi++)
        #pragma unroll
        for (int ni = 0; ni < 4; ni++)
          acc[mi][ni] = __builtin_amdgcn_mfma_f32_16x16x32_bf16(a[mi], b[ni], acc[mi][ni], 0, 0, 0);
    }
  }
}

// ---------------- 3. fused QKV GEMM + RoPE / V-transpose, masked-row cut ----------------
// grid y in [0,34): y<16 -> Q tile y; y<25 -> K tile map[y-16]; else V tile map[y-25]
// where map = {0,1,9..15} (only M-tiles containing kept key rows [0,224)U[1216,2048)).
__global__ __launch_bounds__(256, 3) void gemm_qkv_kernel(
    const unsigned short* __restrict__ hsb, const unsigned short* __restrict__ wqb,
    const unsigned short* __restrict__ wkb, const unsigned short* __restrict__ wvb,
    const float* __restrict__ cst, const float* __restrict__ snt,
    unsigned short* __restrict__ qbf, unsigned short* __restrict__ kbf,
    unsigned short* __restrict__ vbT) {
  __shared__ __align__(16) unsigned short LDSBUF[17408];  // As(16KB)+Bs(16KB); vtile reuses
  unsigned short* As = LDSBUF;
  unsigned short* Bs = LDSBUF + 8192;
  int y = blockIdx.y;
  int z, mi;
  if (y < 16)      { z = 0; mi = y; }
  else if (y < 25) { z = 1; mi = y - 16; }
  else             { z = 2; mi = y - 25; }
  if (z) mi = (mi < 2) ? mi : mi + 7;
  const unsigned short* B = (z == 0) ? wqb : (z == 1) ? wkb : wvb;
  int m0 = mi * 128, n0 = blockIdx.x * 128;
  f32x4 acc[4][4];
  gemm_mainloop64(hsb, B, As, Bs, m0, n0, 0, DM / 64, threadIdx.x, acc);
  int tid = threadIdx.x, w = tid >> 6, lane = tid & 63;
  int wm = w >> 1, wn = w & 1, q4 = lane >> 4, r = lane & 15;
  int h = n0 >> 7;
  if (z < 2) {
    unsigned short* dst = (z == 0) ? qbf : kbf;
    #pragma unroll
    for (int mj = 0; mj < 4; mj++)
      #pragma unroll
      for (int p = 0; p < 2; p++) {
        int d = wn * 32 + p * 16 + r;
        #pragma unroll
        for (int g = 0; g < 4; g++) {
          int t = m0 + wm * 64 + mj * 16 + q4 * 4 + g;
          float c = cst[t * 64 + d], s = snt[t * 64 + d];
          float x0 = acc[mj][2 * p][g], x1 = acc[mj][2 * p + 1][g];
          dst[((size_t)h * T_SEQ + t) * HD + d]      = f2bf(x0 * c - x1 * s);
          dst[((size_t)h * T_SEQ + t) * HD + d + 64] = f2bf(x1 * c + x0 * s);
        }
      }
  } else {
    // transpose C tile (t,d) -> vbT[h][d][t] via LDS (Tpad=136)
    __syncthreads();
    #pragma unroll
    for (int mj = 0; mj < 4; mj++)
      #pragma unroll
      for (int ni = 0; ni < 4; ni++) {
        int c = (ni & 1) * 64 + wn * 32 + (ni >> 1) * 16 + r;
        int tl = wm * 64 + mj * 16 + q4 * 4;
        short4v pv;
        pv[0] = (short)f2bf(acc[mj][ni][0]);
        pv[1] = (short)f2bf(acc[mj][ni][1]);
        pv[2] = (short)f2bf(acc[mj][ni][2]);
        pv[3] = (short)f2bf(acc[mj][ni][3]);
        *(short4v*)(LDSBUF + c * 136 + tl) = pv;
      }
    __syncthreads();
    int d = tid >> 1, th = tid & 1;
    unsigned short* gdst = vbT + ((size_t)h * HD + d) * T_SEQ + m0 + th * 64;
    const unsigned short* lsrc = LDSBUF + d * 136 + th * 64;
    #pragma unroll
    for (int j = 0; j < 8; j++)
      *(short8*)(gdst + j * 8) = *(const short8*)(lsrc + j * 8);
  }
}

// ---------------- 4. flash attention, 64-key super-chunks, cross-iter dbuf ----------------
__device__ __forceinline__ void attn_body(
    int kb, const unsigned short* Kt, const unsigned short* Vt,
    const unsigned short* indv, unsigned short* Psw,
    const short8 (&aq)[4], f32x4 (&o)[8], f32x4& o9, float (&evf)[4],
    int q4, int r) {
  f32x4 zero = {0.f, 0.f, 0.f, 0.f};
  int rsw = (r >> 1) & 3;
  f32x4 s0 = zero, s1 = zero;
  #pragma unroll
  for (int c = 0; c < 4; c++) {
    int pc = ((c * 4 + q4) ^ r) * 8;
    short8 bk0 = *(const short8*)(Kt + r * 128 + pc);
    short8 bk1 = *(const short8*)(Kt + (16 + r) * 128 + pc);
    s0 = __builtin_amdgcn_mfma_f32_16x16x32_bf16(aq[c], bk0, s0, 0, 0, 0);
    s1 = __builtin_amdgcn_mfma_f32_16x16x32_bf16(aq[c], bk1, s1, 0, 0, 0);
  }
  int kg0 = kb + r, kg1 = kb + 16 + r;
  bool keep0 = (kg0 < SB) || (kg0 >= EV);
  bool keep1 = (kg1 < SB) || (kg1 >= EV);
  #pragma unroll
  for (int g = 0; g < 4; g++) {
    float p0 = keep0 ? __expf(fmaf(s0[g], SCALE, -8.0f)) : 0.0f;
    float p1 = keep1 ? __expf(fmaf(s1[g], SCALE, -8.0f)) : 0.0f;
    if (kb == 1216 && kg0 == EV) evf[g] = p0;   // fp32 capture of p(k=1229)
    int row = q4 * 4 + g;
    int psw = (row >> 1) & 3;
    Psw[row * 32 + (((r >> 3) ^ psw) * 8) + (r & 7)]       = f2bf(p0);
    Psw[row * 32 + ((((r >> 3) + 2) ^ psw) * 8) + (r & 7)] = f2bf(p1);
  }
  short8 pa = *(const short8*)(Psw + r * 32 + (q4 ^ rsw) * 8);
  #pragma unroll
  for (int ni = 0; ni < 8; ni++) {
    short8 bv = *(const short8*)(Vt + (ni * 16 + r) * 32 + (q4 ^ rsw) * 8);
    o[ni] = __builtin_amdgcn_mfma_f32_16x16x32_bf16(pa, bv, o[ni], 0, 0, 0);
  }
  short8 bind = *(const short8*)(indv + r * 32 + (q4 ^ rsw) * 8);
  o9 = __builtin_amdgcn_mfma_f32_16x16x32_bf16(pa, bind, o9, 0, 0, 0);
}

__global__ __launch_bounds__(256, 2) void attn_kernel(
    const unsigned short* __restrict__ qbf, const unsigned short* __restrict__ kbf,
    const unsigned short* __restrict__ vbT, unsigned short* __restrict__ atb,
    float* __restrict__ attnf_s, float* __restrict__ Ssum, float* __restrict__ lst) {
  __shared__ __align__(16) unsigned short KtS[2][2][4096];  // [dbuf][sub][32x128u]
  __shared__ __align__(16) unsigned short VtS[2][2][4096];  // [dbuf][sub][128x32u]
  __shared__ __align__(16) unsigned short Ps[4][512];
  __shared__ __align__(16) unsigned short Ind[3 * 512];
  int tid = threadIdx.x, w = tid >> 6, lane = tid & 63;
  int q4 = lane >> 4, r = lane & 15;
  int h = blockIdx.y;
  int qb = blockIdx.x * 64 + w * 16;

  for (int idx = tid; idx < 3 * 512; idx += 256) {
    int v = idx >> 9, n = (idx >> 5) & 15, j = idx & 31;
    float val = 0.f;
    if (n == 0) val = 1.f;
    else if (n == 1) val = (v == 1) ? (j >= 14 ? 1.f : 0.f) : (v == 2 ? 1.f : 0.f);
    Ind[v * 512 + n * 32 + (((j >> 3) ^ ((n >> 1) & 3)) * 8) + (j & 7)] = f2bf(val);
  }

  short8 aq[4];
  {
    const unsigned short* qrow = qbf + ((size_t)h * T_SEQ + qb + r) * HD;
    #pragma unroll
    for (int c = 0; c < 4; c++) aq[c] = *(const short8*)(qrow + c * 32 + q4 * 8);
  }
  f32x4 zero = {0.f, 0.f, 0.f, 0.f};
  f32x4 o[8], o9;
  #pragma unroll
  for (int ni = 0; ni < 8; ni++) o[ni] = zero;
  o9 = zero;
  float evf[4] = {0.f, 0.f, 0.f, 0.f};

  const char* Kbase = (const char*)(kbf + (size_t)h * T_SEQ * HD);
  int krow0 = w * 8 + q4, krow1 = krow0 + 4;
  const char* Kg0 = Kbase + krow0 * 256 + ((r ^ (krow0 & 15)) * 16);
  const char* Kg1 = Kbase + krow1 * 256 + ((r ^ (krow1 & 15)) * 16);
  const char* Vbase = (const char*)(vbT + (size_t)h * HD * T_SEQ);
  int vsrc = ((lane & 3) ^ ((lane >> 3) & 3)) * 16;
  const char* Vg0 = Vbase + (size_t)(w * 32 + (lane >> 2)) * 4096 + vsrc;
  const char* Vg1 = Vg0 + 16 * 4096;

  auto issue_chunk = [&](int ci, int db) {
    int kb = (ci < 4) ? ci * 64 : 1216 + (ci - 4) * 64;
    gload16(Kg0 + kb * 256,         &KtS[db][0][w * 1024]);
    gload16(Kg1 + kb * 256,         &KtS[db][0][w * 1024 + 512]);
    gload16(Kg0 + (kb + 32) * 256,  &KtS[db][1][w * 1024]);
    gload16(Kg1 + (kb + 32) * 256,  &KtS[db][1][w * 1024 + 512]);
    gload16(Vg0 + kb * 2,           &VtS[db][0][w * 1024]);
    gload16(Vg1 + kb * 2,           &VtS[db][0][w * 1024 + 512]);
    gload16(Vg0 + (kb + 32) * 2,    &VtS[db][1][w * 1024]);
    gload16(Vg1 + (kb + 32) * 2,    &VtS[db][1][w * 1024 + 512]);
  };

  issue_chunk(0, 0);
  for (int ci = 0; ci < 17; ci++) {
    int db = ci & 1;
    int kb = (ci < 4) ? ci * 64 : 1216 + (ci - 4) * 64;
    const unsigned short* indA = Ind + ((ci < 4) ? 0 : (ci == 4) ? 512 : 1024);
    const unsigned short* indB = Ind + ((ci < 4) ? 0 : 1024);
    __syncthreads();
    if (ci < 16) issue_chunk(ci + 1, db ^ 1);
    attn_body(kb,      KtS[db][0], VtS[db][0], indA, &Ps[w][0], aq, o, o9, evf, q4, r);
    attn_body(kb + 32, KtS[db][1], VtS[db][1], indB, &Ps[w][0], aq, o, o9, evf, q4, r);
  }

  float invl[4], srn[4], evn[4];
  #pragma unroll
  for (int g = 0; g < 4; g++) {
    float l  = __shfl(o9[g], lane & 48, 64);
    float sr = __shfl(o9[g], (lane & 48) | 1, 64);
    float ev = __shfl(evf[g], (lane & 48) | 13, 64);
    invl[g] = 1.0f / l;
    srn[g] = sr * invl[g];
    evn[g] = ev * invl[g];
  }
  if (blockIdx.x < (LAST_START / 64)) {
    #pragma unroll
    for (int ni = 0; ni < 8; ni++)
      #pragma unroll
      for (int g = 0; g < 4; g++)
        atb[(size_t)(qb + q4 * 4 + g) * DM + h * HD + ni * 16 + r] = f2bf(o[ni][g] * invl[g]);
  } else {
    #pragma unroll
    for (int ni = 0; ni < 8; ni++)
      #pragma unroll
      for (int g = 0; g < 4; g++)
        attnf_s[(size_t)(qb - LAST_START + q4 * 4 + g) * DM + h * HD + ni * 16 + r] = o[ni][g] * invl[g];
  }
  if (r == 0) {
    #pragma unroll
    for (int g = 0; g < 4; g++) {
      int t = qb + q4 * 4 + g;
      if (t >= LAST_START) Ssum[h * 256 + (t - LAST_START)] = srn[g];
      if (t == T_SEQ - 1) { lst[h * 2] = evn[g]; lst[h * 2 + 1] = srn[g]; }
    }
  }
}

// ---------------- 5. rank-1 eviction fixup (rows >= 1792), bern inlined ----------------
__device__ __forceinline__ void tf_round(uint32_t& x0, uint32_t& x1, int rot) {
  x0 += x1;
  x1 = (x1 << rot) | (x1 >> (32 - rot));
  x1 ^= x0;
}
__device__ __forceinline__ float bern_scale(int hh, const float* lst) {
  const uint32_t k0 = 0u, k1 = 42u, k2 = 0x1BD11BDAu ^ k0 ^ k1;
  uint32_t x0 = (uint32_t)(hh & 7), x1 = (uint32_t)((hh & 7) + 8);
  x0 += k0; x1 += k1;
  tf_round(x0, x1, 13); tf_round(x0, x1, 15); tf_round(x0, x1, 26); tf_round(x0, x1, 6);
  x0 += k1; x1 += k2 + 1u;
  tf_round(x0, x1, 17); tf_round(x0, x1, 29); tf_round(x0, x1, 16); tf_round(x0, x1, 24);
  x0 += k2; x1 += k0 + 2u;
  tf_round(x0, x1, 13); tf_round(x0, x1, 15); tf_round(x0, x1, 26); tf_round(x0, x1, 6);
  x0 += k0; x1 += k1 + 3u;
  tf_round(x0, x1, 17); tf_round(x0, x1, 29); tf_round(x0, x1, 16); tf_round(x0, x1, 24);
  x0 += k1; x1 += k2 + 4u;
  tf_round(x0, x1, 13); tf_round(x0, x1, 15); tf_round(x0, x1, 26); tf_round(x0, x1, 6);
  x0 += k2; x1 += k0 + 5u;
  uint32_t bits = (hh < 8) ? x0 : x1;
  float u = __uint_as_float((bits >> 9) | 0x3f800000u) - 1.0f;
  float evp = lst[hh * 2], srp = lst[hh * 2 + 1];
  float mean = srp * (1.0f / NRECF) + 1e-6f;
  float p = evp / mean;
  p = fminf(fmaxf(p, 0.0f), 1.0f);
  if (!(p == p)) p = 0.0f;
  return (u < p) ? (1.0f / (float)RB) : 0.0f;
}

__global__ __launch_bounds__(256) void fixup_kernel(
    const float* __restrict__ attnf_s, const float* __restrict__ Ssum,
    const float* __restrict__ lst, const unsigned short* __restrict__ vbT,
    unsigned short* __restrict__ atb) {
  int idx = blockIdx.x * 256 + threadIdx.x;   // 256*2048
  int t2 = idx >> 11, n = idx & 2047;
  int h = n >> 7, d = n & 127;
  float bsc = bern_scale(h, lst);
  float v = attnf_s[idx];
  v += Ssum[h * 256 + t2] * bsc * bf2f(vbT[((size_t)h * HD + d) * T_SEQ + EV]);
  atb[(size_t)(t2 + LAST_START) * DM + n] = f2bf(v);
}

// ---------------- 6. output projection GEMM, split-K=2, partials ----------------
__global__ __launch_bounds__(256, 3) void gemm_out_kernel(
    const unsigned short* __restrict__ atb, const unsigned short* __restrict__ wob,
    float* __restrict__ part0, float* __restrict__ part1) {
  __shared__ __align__(16) unsigned short LDSBUF[16384];
  unsigned short* As = LDSBUF;
  unsigned short* Bs = LDSBUF + 8192;
  int m0 = blockIdx.y * 128, n0 = blockIdx.x * 128;
  int kz = blockIdx.z;
  float* part = kz ? part1 : part0;
  f32x4 acc[4][4];
  gemm_mainloop64(atb, wob, As, Bs, m0, n0, kz * 1024, 16, threadIdx.x, acc);
  int tid = threadIdx.x, w = tid >> 6, lane = tid & 63;
  int wm = w >> 1, wn = w & 1, q4 = lane >> 4, r = lane & 15;
  #pragma unroll
  for (int mi = 0; mi < 4; mi++)
    #pragma unroll
    for (int ni = 0; ni < 4; ni++) {
      int c = n0 + (ni & 1) * 64 + wn * 32 + (ni >> 1) * 16 + r;
      #pragma unroll
      for (int g = 0; g < 4; g++) {
        int t = m0 + wm * 64 + mi * 16 + q4 * 4 + g;
        part[(size_t)t * DM + c] = acc[mi][ni][g];
      }
    }
}

// ---------------- 7. partial add + nan_to_num ----------------
__global__ __launch_bounds__(256) void add_kernel(
    const float* __restrict__ p0, const float* __restrict__ p1, float* __restrict__ out) {
  int i4 = (blockIdx.x * 256 + threadIdx.x) * 4;
  float4 a = *(const float4*)(p0 + i4);
  float4 b = *(const float4*)(p1 + i4);
  float4 o;
  o.x = n2n(a.x + b.x); o.y = n2n(a.y + b.y);
  o.z = n2n(a.z + b.z); o.w = n2n(a.w + b.w);
  *(float4*)(out + i4) = o;
}

// ---------------- launch ----------------
extern "C" void kernel_launch(void* const* d_in, const int* in_sizes, int n_in,
                              void* d_out, int out_size, void* d_ws, size_t ws_size,
                              hipStream_t stream) {
  const float* hs = (const float*)d_in[0];
  const float* Wq = (const float*)d_in[1];
  const float* Wk = (const float*)d_in[2];
  const float* Wv = (const float*)d_in[3];
  const float* Wo = (const float*)d_in[4];
  char* ws = (char*)d_ws;
  const size_t MB = 1024 * 1024;
  unsigned short* hsb = (unsigned short*)(ws + 0);         // 8 MB
  unsigned short* wqb = (unsigned short*)(ws + 8 * MB);    // 8 MB
  unsigned short* wkb = (unsigned short*)(ws + 16 * MB);   // 8 MB
  unsigned short* wvb = (unsigned short*)(ws + 24 * MB);   // 8 MB
  unsigned short* wob = (unsigned short*)(ws + 32 * MB);   // 8 MB
  unsigned short* qbf = (unsigned short*)(ws + 40 * MB);   // 8 MB
  unsigned short* kbf = (unsigned short*)(ws + 48 * MB);   // 8 MB
  unsigned short* vbT = (unsigned short*)(ws + 56 * MB);   // 8 MB
  unsigned short* atb = (unsigned short*)(ws + 64 * MB);   // 8 MB
  float* attnf_s = (float*)(ws + 72 * MB);                 // 2 MB (rows 1792..2047)
  float* part0 = (float*)(ws + 74 * MB);                   // 16 MB
  float* part1 = (float*)(ws + 90 * MB);                   // 16 MB
  float* cst = (float*)(ws + 106 * MB);                    // 512 KB
  float* snt = (float*)(ws + 106 * MB + 524288);           // 512 KB
  float* Ssum = (float*)(ws + 107 * MB);                   // 16 KB
  float* lst = (float*)(ws + 107 * MB + 16384);            // 128 B

  cvt_kernel<<<20992, 256, 0, stream>>>(hs, Wq, Wk, Wv, Wo, hsb, wqb, wkb, wvb, wob, cst, snt);
  gemm_qkv_kernel<<<dim3(16, 34), 256, 0, stream>>>(hsb, wqb, wkb, wvb, cst, snt, qbf, kbf, vbT);
  attn_kernel<<<dim3(32, 16), 256, 0, stream>>>(qbf, kbf, vbT, atb, attnf_s, Ssum, lst);
  fixup_kernel<<<2048, 256, 0, stream>>>(attnf_s, Ssum, lst, vbT, atb);
  gemm_out_kernel<<<dim3(16, 16, 2), 256, 0, stream>>>(atb, wob, part0, part1);
  add_kernel<<<4096, 256, 0, stream>>>(part0, part1, (float*)d_out);
}